// Round 1
// baseline (346.775 us; speedup 1.0000x reference)
//
#include <hip/hip_runtime.h>
#include <hip/hip_bf16.h>
#include <stdint.h>

#define IN_F 1024
#define OUT_F 1024
#define NG 8
#define KSPLINE 8192            // IN_F * NG
#define KDIM 9216               // KSPLINE + IN_F
#define M_ROWS 8192
#define LOG2E 1.4426950408889634f
#define DENOMV 0.5714285714285714f   // 4/7
#define INV_DENOM 1.75f              // 7/4

using bf16_t = __bf16;
using bf16x8 = __attribute__((ext_vector_type(8))) __bf16;
using f32x4  = __attribute__((ext_vector_type(4))) float;

#define AS1 __attribute__((address_space(1)))
#define AS3 __attribute__((address_space(3)))

__device__ inline unsigned short f2bf(float f) {
    unsigned int u = __float_as_uint(f);
    u += 0x7fffu + ((u >> 16) & 1u);      // round-to-nearest-even
    return (unsigned short)(u >> 16);
}

// ---------------- W = [spline_w | base_w] as bf16, row-major (OUT_F x KDIM) ----
__global__ __launch_bounds__(256) void prep_w_kernel(
        const float* __restrict__ sw, const float* __restrict__ bw,
        bf16_t* __restrict__ W) {
    int idx = blockIdx.x * 256 + threadIdx.x;   // one float4 per thread
    int o   = idx / 2304;                       // 2304 float4 per output row
    int k4  = idx - o * 2304;
    float4 v;
    if (k4 < 2048) v = ((const float4*)sw)[(size_t)o * 2048 + k4];
    else           v = ((const float4*)bw)[(size_t)o * 256 + (k4 - 2048)];
    unsigned int lo = (unsigned int)f2bf(v.x) | ((unsigned int)f2bf(v.y) << 16);
    unsigned int hi = (unsigned int)f2bf(v.z) | ((unsigned int)f2bf(v.w) << 16);
    ((uint2*)W)[idx] = make_uint2(lo, hi);
}

// ---------------- A = [rbf_basis(LN(x)) | silu(x)] as bf16, row-major (rows x KDIM)
__global__ __launch_bounds__(256) void prep_a_kernel(
        const float* __restrict__ x, const float* __restrict__ gamma,
        const float* __restrict__ beta, bf16_t* __restrict__ A) {
    int row = blockIdx.x;
    int tid = threadIdx.x;
    const float4 xv = ((const float4*)(x + (size_t)row * IN_F))[tid];
    float s  = xv.x + xv.y + xv.z + xv.w;
    float s2 = xv.x * xv.x + xv.y * xv.y + xv.z * xv.z + xv.w * xv.w;
#pragma unroll
    for (int off = 32; off > 0; off >>= 1) {
        s  += __shfl_down(s, off);
        s2 += __shfl_down(s2, off);
    }
    __shared__ float red[8];
    int wave = tid >> 6, lane = tid & 63;
    if (lane == 0) { red[wave] = s; red[4 + wave] = s2; }
    __syncthreads();
    s  = red[0] + red[1] + red[2] + red[3];
    s2 = red[4] + red[5] + red[6] + red[7];
    float mu   = s * (1.0f / IN_F);
    float var  = s2 * (1.0f / IN_F) - mu * mu;
    float rstd = rsqrtf(var + 1e-5f);

    bf16_t* Arow = A + (size_t)row * KDIM;
    float xa[4] = {xv.x, xv.y, xv.z, xv.w};
    unsigned short silu_us[4];
#pragma unroll
    for (int j = 0; j < 4; ++j) {
        int f = tid * 4 + j;
        float xs = xa[j];
        float xn = (xs - mu) * rstd * gamma[f] + beta[f];
        unsigned int pk[4];
#pragma unroll
        for (int g = 0; g < 4; ++g) {
            float t0 = (xn - (-2.0f + (float)(2 * g)     * DENOMV)) * INV_DENOM;
            float t1 = (xn - (-2.0f + (float)(2 * g + 1) * DENOMV)) * INV_DENOM;
            float b0 = exp2f(t0 * t0 * -LOG2E);
            float b1 = exp2f(t1 * t1 * -LOG2E);
            pk[g] = (unsigned int)f2bf(b0) | ((unsigned int)f2bf(b1) << 16);
        }
        ((uint4*)(Arow + (size_t)f * NG))[0] = make_uint4(pk[0], pk[1], pk[2], pk[3]);
        float sg = xs / (1.0f + exp2f(-xs * LOG2E));   // silu
        silu_us[j] = f2bf(sg);
    }
    unsigned int slo = (unsigned int)silu_us[0] | ((unsigned int)silu_us[1] << 16);
    unsigned int shi = (unsigned int)silu_us[2] | ((unsigned int)silu_us[3] << 16);
    ((uint2*)(Arow + KSPLINE))[tid] = make_uint2(slo, shi);
}

// ---------------- GEMM: C(rows x 1024) = A(rows x 9216) * W^T + bias ----------
// m97 structure: 128x128 tile, BK=32, 4 waves each 64x64 via 4x4 mfma 16x16x32.
__global__ __launch_bounds__(256, 2) void gemm_kernel(
        const bf16_t* __restrict__ A, const bf16_t* __restrict__ W,
        const float* __restrict__ bias, float* __restrict__ C) {
    __shared__ alignas(16) bf16_t As[128 * 32];   // 8 KB
    __shared__ alignas(16) bf16_t Bs[128 * 32];   // 8 KB
    const int bm = blockIdx.x, bn = blockIdx.y;
    const int tid = threadIdx.x;
    const int wave = tid >> 6, lane = tid & 63;
    const int wm = wave >> 1, wn = wave & 1;

    f32x4 acc[4][4] = {};

    // staging: 8192 B per tile = 512 x 16B chunks; each wave 2 issues of 64 lanes
    const bf16_t* gAj[2];
    const bf16_t* gBj[2];
    int ldsOff[2];
#pragma unroll
    for (int j = 0; j < 2; ++j) {
        int chunk = wave * 128 + j * 64 + lane;    // 0..511
        int r  = chunk >> 2;                       // tile row 0..127
        int c8 = (chunk & 3) * 8;                  // k-offset in elements
        gAj[j] = A + (size_t)(bm * 128 + r) * KDIM + c8;
        gBj[j] = W + (size_t)(bn * 128 + r) * KDIM + c8;
        ldsOff[j] = chunk * 8;                     // element offset in LDS tile
    }

    const int lm = lane & 15;
    const int lk = (lane >> 4) * 8;

    for (int kt = 0; kt < KDIM / 32; ++kt) {
        __syncthreads();   // previous iter's ds_reads done before overwrite
#pragma unroll
        for (int j = 0; j < 2; ++j) {
            __builtin_amdgcn_global_load_lds(
                (const AS1 void*)(gAj[j] + kt * 32), (AS3 void*)(As + ldsOff[j]), 16, 0, 0);
            __builtin_amdgcn_global_load_lds(
                (const AS1 void*)(gBj[j] + kt * 32), (AS3 void*)(Bs + ldsOff[j]), 16, 0, 0);
        }
        __syncthreads();   // staging complete

        bf16x8 a[4], b[4];
#pragma unroll
        for (int i = 0; i < 4; ++i) {
            a[i] = *(const bf16x8*)(As + (wm * 64 + i * 16 + lm) * 32 + lk);
            b[i] = *(const bf16x8*)(Bs + (wn * 64 + i * 16 + lm) * 32 + lk);
        }
#pragma unroll
        for (int mi = 0; mi < 4; ++mi)
#pragma unroll
            for (int ni = 0; ni < 4; ++ni)
                acc[mi][ni] = __builtin_amdgcn_mfma_f32_16x16x32_bf16(
                    a[mi], b[ni], acc[mi][ni], 0, 0, 0);
    }

    // epilogue: C/D layout col = lane&15, row = (lane>>4)*4 + reg
    const int cn = lane & 15;
    const int rm = (lane >> 4) * 4;
#pragma unroll
    for (int ni = 0; ni < 4; ++ni) {
        int col = bn * 128 + wn * 64 + ni * 16 + cn;
        float bv = bias[col];
#pragma unroll
        for (int mi = 0; mi < 4; ++mi) {
            int row = bm * 128 + wm * 64 + mi * 16 + rm;
            float* Cp = C + (size_t)row * OUT_F + col;
#pragma unroll
            for (int r = 0; r < 4; ++r)
                Cp[(size_t)r * OUT_F] = acc[mi][ni][r] + bv;
        }
    }
}

extern "C" void kernel_launch(void* const* d_in, const int* in_sizes, int n_in,
                              void* d_out, int out_size, void* d_ws, size_t ws_size,
                              hipStream_t stream) {
    const float* x     = (const float*)d_in[0];
    const float* gamma = (const float*)d_in[1];
    const float* beta  = (const float*)d_in[2];
    const float* sw    = (const float*)d_in[3];
    const float* bw    = (const float*)d_in[4];
    const float* bb    = (const float*)d_in[5];
    float* out = (float*)d_out;

    char* ws = (char*)d_ws;
    const size_t Wbytes = (size_t)OUT_F * KDIM * 2;   // 18.9 MB
    bf16_t* Wb = (bf16_t*)ws;
    bf16_t* Ab = (bf16_t*)(ws + Wbytes);

    const size_t rowBytes = (size_t)KDIM * 2;
    size_t avail = ws_size > Wbytes ? ws_size - Wbytes : 0;
    int chunk = (int)(avail / rowBytes);
    chunk &= ~127;                       // multiple of 128 rows
    if (chunk > M_ROWS) chunk = M_ROWS;
    if (chunk < 128) chunk = 128;        // last resort; needs ~21 MB ws

    prep_w_kernel<<<(OUT_F * 2304) / 256, 256, 0, stream>>>(sw, bw, Wb);

    for (int r0 = 0; r0 < M_ROWS; r0 += chunk) {
        int rows = (M_ROWS - r0) < chunk ? (M_ROWS - r0) : chunk;
        prep_a_kernel<<<rows, 256, 0, stream>>>(x + (size_t)r0 * IN_F, gamma, beta, Ab);
        dim3 g(rows / 128, OUT_F / 128);
        gemm_kernel<<<g, dim3(256), 0, stream>>>(Ab, Wb, bb, out + (size_t)r0 * OUT_F);
    }
}

// Round 2
// 345.156 us; speedup vs baseline: 1.0047x; 1.0047x over previous
//
#include <hip/hip_runtime.h>
#include <hip/hip_bf16.h>
#include <stdint.h>

#define IN_F 1024
#define OUT_F 1024
#define NG 8
#define KSPLINE 8192            // IN_F * NG
#define KDIM 9216               // KSPLINE + IN_F
#define M_ROWS 8192
#define SPLITK 2
#define KHALF (KDIM / SPLITK)   // 4608
#define LOG2E 1.4426950408889634f
#define DENOMV 0.5714285714285714f   // 4/7
#define INV_DENOM 1.75f              // 7/4

using bf16_t = __bf16;
using bf16x8 = __attribute__((ext_vector_type(8))) __bf16;
using f32x4  = __attribute__((ext_vector_type(4))) float;

#define AS1 __attribute__((address_space(1)))
#define AS3 __attribute__((address_space(3)))

__device__ inline unsigned short f2bf(float f) {
    unsigned int u = __float_as_uint(f);
    u += 0x7fffu + ((u >> 16) & 1u);      // round-to-nearest-even
    return (unsigned short)(u >> 16);
}

// ---------------- W = [spline_w | base_w] as bf16, row-major (OUT_F x KDIM) ----
__global__ __launch_bounds__(256) void prep_w_kernel(
        const float* __restrict__ sw, const float* __restrict__ bw,
        bf16_t* __restrict__ W) {
    int idx = blockIdx.x * 256 + threadIdx.x;   // one float4 per thread
    int o   = idx / 2304;                       // 2304 float4 per output row
    int k4  = idx - o * 2304;
    float4 v;
    if (k4 < 2048) v = ((const float4*)sw)[(size_t)o * 2048 + k4];
    else           v = ((const float4*)bw)[(size_t)o * 256 + (k4 - 2048)];
    unsigned int lo = (unsigned int)f2bf(v.x) | ((unsigned int)f2bf(v.y) << 16);
    unsigned int hi = (unsigned int)f2bf(v.z) | ((unsigned int)f2bf(v.w) << 16);
    ((uint2*)W)[idx] = make_uint2(lo, hi);
}

// ---------------- A = [rbf_basis(LN(x)) | silu(x)] as bf16, row-major (rows x KDIM)
// Thread t handles features {t, 256+t, 512+t, 768+t} so that every 16B basis
// store is lane-contiguous (full 4KB/wave per store instruction).
__global__ __launch_bounds__(256) void prep_a_kernel(
        const float* __restrict__ x, const float* __restrict__ gamma,
        const float* __restrict__ beta, bf16_t* __restrict__ A) {
    int row = blockIdx.x;
    int tid = threadIdx.x;
    const float* xr = x + (size_t)row * IN_F;
    float xv[4];
#pragma unroll
    for (int j = 0; j < 4; ++j) xv[j] = xr[j * 256 + tid];
    float s  = xv[0] + xv[1] + xv[2] + xv[3];
    float s2 = xv[0]*xv[0] + xv[1]*xv[1] + xv[2]*xv[2] + xv[3]*xv[3];
#pragma unroll
    for (int off = 32; off > 0; off >>= 1) {
        s  += __shfl_down(s, off);
        s2 += __shfl_down(s2, off);
    }
    __shared__ float red[8];
    int wave = tid >> 6, lane = tid & 63;
    if (lane == 0) { red[wave] = s; red[4 + wave] = s2; }
    __syncthreads();
    s  = red[0] + red[1] + red[2] + red[3];
    s2 = red[4] + red[5] + red[6] + red[7];
    float mu   = s * (1.0f / IN_F);
    float var  = s2 * (1.0f / IN_F) - mu * mu;
    float rstd = rsqrtf(var + 1e-5f);

    bf16_t* Arow = A + (size_t)row * KDIM;
    uint4* basis_out = (uint4*)Arow;                        // chunk f = feature f
    unsigned short* silu_out = (unsigned short*)(Arow + KSPLINE);
#pragma unroll
    for (int j = 0; j < 4; ++j) {
        int f = j * 256 + tid;
        float xs = xv[j];
        float xn = (xs - mu) * rstd * gamma[f] + beta[f];
        unsigned int pk[4];
#pragma unroll
        for (int g = 0; g < 4; ++g) {
            float t0 = (xn - (-2.0f + (float)(2 * g)     * DENOMV)) * INV_DENOM;
            float t1 = (xn - (-2.0f + (float)(2 * g + 1) * DENOMV)) * INV_DENOM;
            float b0 = exp2f(t0 * t0 * -LOG2E);
            float b1 = exp2f(t1 * t1 * -LOG2E);
            pk[g] = (unsigned int)f2bf(b0) | ((unsigned int)f2bf(b1) << 16);
        }
        basis_out[f] = make_uint4(pk[0], pk[1], pk[2], pk[3]);
        float sg = xs / (1.0f + exp2f(-xs * LOG2E));   // silu
        silu_out[f] = f2bf(sg);
    }
}

// ---------------- GEMM: C(rows x 1024) += A(rows x 9216) * W^T (+ bias) ------
// m97 structure: 128x128 tile, BK=32, 4 waves each 64x64 via 4x4 mfma 16x16x32.
// Split-K x2 over blockIdx.z for 4 blocks/CU co-residency; fp32 atomicAdd
// epilogue onto pre-zeroed C; bias folded into split 0.
__global__ __launch_bounds__(256, 4) void gemm_kernel(
        const bf16_t* __restrict__ A, const bf16_t* __restrict__ W,
        const float* __restrict__ bias, float* __restrict__ C) {
    __shared__ alignas(16) bf16_t As[128 * 32];   // 8 KB
    __shared__ alignas(16) bf16_t Bs[128 * 32];   // 8 KB
    const int bm = blockIdx.x, bn = blockIdx.y, bz = blockIdx.z;
    const int tid = threadIdx.x;
    const int wave = tid >> 6, lane = tid & 63;
    const int wm = wave >> 1, wn = wave & 1;
    const int k0 = bz * KHALF;

    f32x4 acc[4][4] = {};

    // staging: 8192 B per tile = 512 x 16B chunks; each wave 2 issues of 64 lanes
    const bf16_t* gAj[2];
    const bf16_t* gBj[2];
    int ldsOff[2];
#pragma unroll
    for (int j = 0; j < 2; ++j) {
        int chunk = wave * 128 + j * 64 + lane;    // 0..511
        int r  = chunk >> 2;                       // tile row 0..127
        int c8 = (chunk & 3) * 8;                  // k-offset in elements
        gAj[j] = A + (size_t)(bm * 128 + r) * KDIM + k0 + c8;
        gBj[j] = W + (size_t)(bn * 128 + r) * KDIM + k0 + c8;
        ldsOff[j] = chunk * 8;                     // element offset in LDS tile
    }

    const int lm = lane & 15;
    const int lk = (lane >> 4) * 8;

    for (int kt = 0; kt < KHALF / 32; ++kt) {
        __syncthreads();   // previous iter's ds_reads done before overwrite
#pragma unroll
        for (int j = 0; j < 2; ++j) {
            __builtin_amdgcn_global_load_lds(
                (const AS1 void*)(gAj[j] + kt * 32), (AS3 void*)(As + ldsOff[j]), 16, 0, 0);
            __builtin_amdgcn_global_load_lds(
                (const AS1 void*)(gBj[j] + kt * 32), (AS3 void*)(Bs + ldsOff[j]), 16, 0, 0);
        }
        __syncthreads();   // staging complete

        bf16x8 a[4], b[4];
#pragma unroll
        for (int i = 0; i < 4; ++i) {
            a[i] = *(const bf16x8*)(As + (wm * 64 + i * 16 + lm) * 32 + lk);
            b[i] = *(const bf16x8*)(Bs + (wn * 64 + i * 16 + lm) * 32 + lk);
        }
#pragma unroll
        for (int mi = 0; mi < 4; ++mi)
#pragma unroll
            for (int ni = 0; ni < 4; ++ni)
                acc[mi][ni] = __builtin_amdgcn_mfma_f32_16x16x32_bf16(
                    a[mi], b[ni], acc[mi][ni], 0, 0, 0);
    }

    // epilogue: C/D layout col = lane&15, row = (lane>>4)*4 + reg
    const int cn = lane & 15;
    const int rm = (lane >> 4) * 4;
#pragma unroll
    for (int ni = 0; ni < 4; ++ni) {
        int col = bn * 128 + wn * 64 + ni * 16 + cn;
        float bv = (bz == 0) ? bias[col] : 0.0f;
#pragma unroll
        for (int mi = 0; mi < 4; ++mi) {
            int row = bm * 128 + wm * 64 + mi * 16 + rm;
            float* Cp = C + (size_t)row * OUT_F + col;
#pragma unroll
            for (int r = 0; r < 4; ++r)
                atomicAdd(Cp + (size_t)r * OUT_F, acc[mi][ni][r] + bv);
        }
    }
}

extern "C" void kernel_launch(void* const* d_in, const int* in_sizes, int n_in,
                              void* d_out, int out_size, void* d_ws, size_t ws_size,
                              hipStream_t stream) {
    const float* x     = (const float*)d_in[0];
    const float* gamma = (const float*)d_in[1];
    const float* beta  = (const float*)d_in[2];
    const float* sw    = (const float*)d_in[3];
    const float* bw    = (const float*)d_in[4];
    const float* bb    = (const float*)d_in[5];
    float* out = (float*)d_out;

    char* ws = (char*)d_ws;
    const size_t Wbytes = (size_t)OUT_F * KDIM * 2;   // 18.9 MB
    bf16_t* Wb = (bf16_t*)ws;
    bf16_t* Ab = (bf16_t*)(ws + Wbytes);

    const size_t rowBytes = (size_t)KDIM * 2;
    size_t avail = ws_size > Wbytes ? ws_size - Wbytes : 0;
    int chunk = (int)(avail / rowBytes);
    chunk &= ~127;                       // multiple of 128 rows
    if (chunk > M_ROWS) chunk = M_ROWS;
    if (chunk < 128) chunk = 128;        // last resort; needs ~21 MB ws

    hipMemsetAsync(out, 0, (size_t)out_size * sizeof(float), stream);

    prep_w_kernel<<<(OUT_F * 2304) / 256, 256, 0, stream>>>(sw, bw, Wb);

    for (int r0 = 0; r0 < M_ROWS; r0 += chunk) {
        int rows = (M_ROWS - r0) < chunk ? (M_ROWS - r0) : chunk;
        prep_a_kernel<<<rows, 256, 0, stream>>>(x + (size_t)r0 * IN_F, gamma, beta, Ab);
        dim3 g(rows / 128, OUT_F / 128, SPLITK);
        gemm_kernel<<<g, dim3(256), 0, stream>>>(Ab, Wb, bb, out + (size_t)r0 * OUT_F);
    }
}

// Round 3
// 334.594 us; speedup vs baseline: 1.0364x; 1.0316x over previous
//
#include <hip/hip_runtime.h>
#include <hip/hip_bf16.h>
#include <stdint.h>

#define IN_F 1024
#define OUT_F 1024
#define NG 8
#define KSPLINE 8192            // IN_F * NG
#define KDIM 9216               // KSPLINE + IN_F
#define M_ROWS 8192
#define LOG2E 1.4426950408889634f
#define DENOMV 0.5714285714285714f   // 4/7
#define INV_DENOM 1.75f              // 7/4

using bf16_t = __bf16;
using bf16x8 = __attribute__((ext_vector_type(8))) __bf16;
using f32x4  = __attribute__((ext_vector_type(4))) float;

#define AS1 __attribute__((address_space(1)))
#define AS3 __attribute__((address_space(3)))

__device__ inline unsigned short f2bf(float f) {
    unsigned int u = __float_as_uint(f);
    u += 0x7fffu + ((u >> 16) & 1u);      // round-to-nearest-even
    return (unsigned short)(u >> 16);
}

// ---------------- W = [spline_w | base_w] as bf16, row-major (OUT_F x KDIM) ----
__global__ __launch_bounds__(256) void prep_w_kernel(
        const float* __restrict__ sw, const float* __restrict__ bw,
        bf16_t* __restrict__ W) {
    int idx = blockIdx.x * 256 + threadIdx.x;   // one float4 per thread
    int o   = idx / 2304;                       // 2304 float4 per output row
    int k4  = idx - o * 2304;
    float4 v;
    if (k4 < 2048) v = ((const float4*)sw)[(size_t)o * 2048 + k4];
    else           v = ((const float4*)bw)[(size_t)o * 256 + (k4 - 2048)];
    unsigned int lo = (unsigned int)f2bf(v.x) | ((unsigned int)f2bf(v.y) << 16);
    unsigned int hi = (unsigned int)f2bf(v.z) | ((unsigned int)f2bf(v.w) << 16);
    ((uint2*)W)[idx] = make_uint2(lo, hi);
}

// ---------------- A = [rbf_basis(LN(x)) | silu(x)] as bf16, row-major ---------
// One wave per row (4 rows/block): no LDS, no __syncthreads, in-wave shfl
// reduction. Lane handles features f = j*64+lane (j=0..15) so each basis
// store instruction writes 64 lanes x 16B = 1KB contiguous; silu stores are
// 128B contiguous per instruction.
__global__ __launch_bounds__(256) void prep_a_kernel(
        const float* __restrict__ x, const float* __restrict__ gamma,
        const float* __restrict__ beta, bf16_t* __restrict__ A) {
    const int wave = threadIdx.x >> 6, lane = threadIdx.x & 63;
    const int row = blockIdx.x * 4 + wave;
    const float* xr = x + (size_t)row * IN_F;

    float xv[16];
    float s = 0.0f, s2 = 0.0f;
#pragma unroll
    for (int j = 0; j < 16; ++j) {
        float v = xr[j * 64 + lane];
        xv[j] = v;
        s += v;
        s2 += v * v;
    }
#pragma unroll
    for (int off = 32; off > 0; off >>= 1) {
        s  += __shfl_xor(s, off);
        s2 += __shfl_xor(s2, off);
    }
    float mu   = s * (1.0f / IN_F);
    float var  = s2 * (1.0f / IN_F) - mu * mu;
    float rstd = rsqrtf(var + 1e-5f);

    bf16_t* Arow = A + (size_t)row * KDIM;
    uint4* basis_out = (uint4*)Arow;                       // chunk f = feature f
    unsigned short* silu_out = (unsigned short*)(Arow + KSPLINE);
#pragma unroll
    for (int j = 0; j < 16; ++j) {
        int f = j * 64 + lane;
        float xs = xv[j];
        float xn = (xs - mu) * rstd * gamma[f] + beta[f];
        unsigned int pk[4];
#pragma unroll
        for (int g = 0; g < 4; ++g) {
            float t0 = (xn - (-2.0f + (float)(2 * g)     * DENOMV)) * INV_DENOM;
            float t1 = (xn - (-2.0f + (float)(2 * g + 1) * DENOMV)) * INV_DENOM;
            float b0 = exp2f(t0 * t0 * -LOG2E);
            float b1 = exp2f(t1 * t1 * -LOG2E);
            pk[g] = (unsigned int)f2bf(b0) | ((unsigned int)f2bf(b1) << 16);
        }
        basis_out[f] = make_uint4(pk[0], pk[1], pk[2], pk[3]);
        float sg = xs / (1.0f + exp2f(-xs * LOG2E));   // silu
        silu_out[f] = f2bf(sg);
    }
}

// ---------------- GEMM: C(rows x 1024) = A(rows x 9216) * W^T + bias ----------
// m97 structure: 128x128 tile, BK=32, 4 waves each 64x64 via 4x4 mfma 16x16x32.
__global__ __launch_bounds__(256, 2) void gemm_kernel(
        const bf16_t* __restrict__ A, const bf16_t* __restrict__ W,
        const float* __restrict__ bias, float* __restrict__ C) {
    __shared__ alignas(16) bf16_t As[128 * 32];   // 8 KB
    __shared__ alignas(16) bf16_t Bs[128 * 32];   // 8 KB
    const int bm = blockIdx.x, bn = blockIdx.y;
    const int tid = threadIdx.x;
    const int wave = tid >> 6, lane = tid & 63;
    const int wm = wave >> 1, wn = wave & 1;

    f32x4 acc[4][4] = {};

    // staging: 8192 B per tile = 512 x 16B chunks; each wave 2 issues of 64 lanes
    const bf16_t* gAj[2];
    const bf16_t* gBj[2];
    int ldsOff[2];
#pragma unroll
    for (int j = 0; j < 2; ++j) {
        int chunk = wave * 128 + j * 64 + lane;    // 0..511
        int r  = chunk >> 2;                       // tile row 0..127
        int c8 = (chunk & 3) * 8;                  // k-offset in elements
        gAj[j] = A + (size_t)(bm * 128 + r) * KDIM + c8;
        gBj[j] = W + (size_t)(bn * 128 + r) * KDIM + c8;
        ldsOff[j] = chunk * 8;                     // element offset in LDS tile
    }

    const int lm = lane & 15;
    const int lk = (lane >> 4) * 8;

    for (int kt = 0; kt < KDIM / 32; ++kt) {
        __syncthreads();   // previous iter's ds_reads done before overwrite
#pragma unroll
        for (int j = 0; j < 2; ++j) {
            __builtin_amdgcn_global_load_lds(
                (const AS1 void*)(gAj[j] + kt * 32), (AS3 void*)(As + ldsOff[j]), 16, 0, 0);
            __builtin_amdgcn_global_load_lds(
                (const AS1 void*)(gBj[j] + kt * 32), (AS3 void*)(Bs + ldsOff[j]), 16, 0, 0);
        }
        __syncthreads();   // staging complete

        bf16x8 a[4], b[4];
#pragma unroll
        for (int i = 0; i < 4; ++i) {
            a[i] = *(const bf16x8*)(As + (wm * 64 + i * 16 + lm) * 32 + lk);
            b[i] = *(const bf16x8*)(Bs + (wn * 64 + i * 16 + lm) * 32 + lk);
        }
#pragma unroll
        for (int mi = 0; mi < 4; ++mi)
#pragma unroll
            for (int ni = 0; ni < 4; ++ni)
                acc[mi][ni] = __builtin_amdgcn_mfma_f32_16x16x32_bf16(
                    a[mi], b[ni], acc[mi][ni], 0, 0, 0);
    }

    // epilogue: C/D layout col = lane&15, row = (lane>>4)*4 + reg
    const int cn = lane & 15;
    const int rm = (lane >> 4) * 4;
#pragma unroll
    for (int ni = 0; ni < 4; ++ni) {
        int col = bn * 128 + wn * 64 + ni * 16 + cn;
        float bv = bias[col];
#pragma unroll
        for (int mi = 0; mi < 4; ++mi) {
            int row = bm * 128 + wm * 64 + mi * 16 + rm;
            float* Cp = C + (size_t)row * OUT_F + col;
#pragma unroll
            for (int r = 0; r < 4; ++r)
                Cp[(size_t)r * OUT_F] = acc[mi][ni][r] + bv;
        }
    }
}

extern "C" void kernel_launch(void* const* d_in, const int* in_sizes, int n_in,
                              void* d_out, int out_size, void* d_ws, size_t ws_size,
                              hipStream_t stream) {
    const float* x     = (const float*)d_in[0];
    const float* gamma = (const float*)d_in[1];
    const float* beta  = (const float*)d_in[2];
    const float* sw    = (const float*)d_in[3];
    const float* bw    = (const float*)d_in[4];
    const float* bb    = (const float*)d_in[5];
    float* out = (float*)d_out;

    char* ws = (char*)d_ws;
    const size_t Wbytes = (size_t)OUT_F * KDIM * 2;   // 18.9 MB
    bf16_t* Wb = (bf16_t*)ws;
    bf16_t* Ab = (bf16_t*)(ws + Wbytes);

    const size_t rowBytes = (size_t)KDIM * 2;
    size_t avail = ws_size > Wbytes ? ws_size - Wbytes : 0;
    int chunk = (int)(avail / rowBytes);
    chunk &= ~127;                       // multiple of 128 rows
    if (chunk > M_ROWS) chunk = M_ROWS;
    if (chunk < 128) chunk = 128;        // last resort; needs ~21 MB ws

    prep_w_kernel<<<(OUT_F * 2304) / 256, 256, 0, stream>>>(sw, bw, Wb);

    for (int r0 = 0; r0 < M_ROWS; r0 += chunk) {
        int rows = (M_ROWS - r0) < chunk ? (M_ROWS - r0) : chunk;
        prep_a_kernel<<<rows / 4, 256, 0, stream>>>(x + (size_t)r0 * IN_F, gamma, beta, Ab);
        dim3 g(rows / 128, OUT_F / 128);
        gemm_kernel<<<g, dim3(256), 0, stream>>>(Ab, Wb, bb, out + (size_t)r0 * OUT_F);
    }
}